// Round 2
// 560.124 us; speedup vs baseline: 1.1254x; 1.1254x over previous
//
#include <hip/hip_runtime.h>

// SelfAttention (Galerkin linear attention), round 4 (resubmit — R1 bench was
// a GPUAcquisitionTimeout, no signal).
// Algebra: qk_in = x + pos ; K = qk_in Wk^T + bk ; V = x Wv^T + bv
//          (per-head LN on K,V) ; S'_h = K_h^T V_h / n
//          W2[he][r] = sum_d Wq[hd][r] S'[d][e] ; b2[he] = sum_d bq[hd] S'[d][e]
//          out = LN(2*(qk_in W2^T + b2)) stored NCHW.
// R4: kv_scores was latency-bound (MfmaUtil 6%, occ 22%): direct-global MFMA
//     operands re-loaded 4x across waves + 8M atomicAdds. Now: qkT/xT stored
//     XOR-swizzled (chunk ^ (row&7)) by prep_qx; kv_scores stages 128x64
//     k-chunks via global_load_lds (linear dest, pre-swizzled source ->
//     conflict-free ds_read_b128), shared by all 4 waves; 4 n-tiles per block
//     accumulated before one atomicAdd (atomic traffic /4). out_kernel reads
//     qkT with the same XOR. Workspace layout unchanged from R3.

typedef float floatx4 __attribute__((ext_vector_type(4)));
typedef __bf16 bf16x8 __attribute__((ext_vector_type(8)));
typedef unsigned short ushortx8 __attribute__((ext_vector_type(8)));
typedef unsigned short ushort;

static __device__ __forceinline__ ushort f2bf(float f) {
  unsigned int u = __builtin_bit_cast(unsigned int, f);
  u += 0x7FFFu + ((u >> 16) & 1u);  // RNE
  return (ushort)(u >> 16);
}
static __device__ __forceinline__ floatx4 mfma16(bf16x8 a, bf16x8 b, floatx4 c) {
  return __builtin_amdgcn_mfma_f32_16x16x32_bf16(a, b, c, 0, 0, 0);
}
static __device__ __forceinline__ bf16x8 frag(const ushort* p) {
  return *(const bf16x8*)p;  // 16-B aligned by construction -> dwordx4
}
typedef __attribute__((address_space(3))) unsigned int as3_u32;
typedef __attribute__((address_space(1))) const unsigned int as1_u32;
static __device__ __forceinline__ void gl_lds16(const ushort* g, ushort* l) {
  // async global->LDS, 16B/lane; LDS dest is wave-uniform base + lane*16
  __builtin_amdgcn_global_load_lds((as1_u32*)g, (as3_u32*)l, 16, 0, 0);
}

// ---------------------------------------------------------------------------
// Wk, Wv fp32 -> bf16 (plain [oc][256]).
__global__ __launch_bounds__(256) void prep_w(const float* __restrict__ Wk,
                                              const float* __restrict__ Wv,
                                              ushort* __restrict__ Wkbf,
                                              ushort* __restrict__ Wvbf) {
  const int i = (int)blockIdx.x * 256 + (int)threadIdx.x;
  float4 a = ((const float4*)Wk)[i];
  float4 b = ((const float4*)Wv)[i];
  ushort4 ua = {f2bf(a.x), f2bf(a.y), f2bf(a.z), f2bf(a.w)};
  ushort4 ub = {f2bf(b.x), f2bf(b.y), f2bf(b.z), f2bf(b.w)};
  ((ushort4*)Wkbf)[i] = ua;
  ((ushort4*)Wvbf)[i] = ub;
}

// ---------------------------------------------------------------------------
// For batch b0+z: qkT[z][n][k] = bf16(x+pos), xT[z][n][k] = bf16(x).
// SWIZZLED store: within each 64-elem (128B) k-chunk, the 8-elem (16B)
// sub-chunk p is stored at position p ^ (n&7). kv_scores' linear
// global_load_lds then lands a conflict-free-readable tile in LDS.
__global__ __launch_bounds__(256) void prep_qx(const float* __restrict__ x,
                                               ushort* __restrict__ qkT,
                                               ushort* __restrict__ xT, int b0) {
  __shared__ float tile[64 * 68];
  const int t = (int)threadIdx.x;
  const int z = (int)blockIdx.y;
  const int b = b0 + z;
  const int n0 = (int)blockIdx.x * 64;
  const float* xb = x + (size_t)b * 256 * 16384;
  ushort* qb = qkT + (size_t)z * 16384 * 256;
  ushort* xtb = xT + (size_t)z * 16384 * 256;
  for (int kc = 0; kc < 4; ++kc) {
    if (kc) __syncthreads();
    const int nn = (t & 15) * 4;
    const int r0 = t >> 4;
#pragma unroll
    for (int it = 0; it < 4; ++it) {
      const int k = r0 + it * 16;
      const float4 v = *(const float4*)(xb + (size_t)(kc * 64 + k) * 16384 + n0 + nn);
      tile[(nn + 0) * 68 + k] = v.x;
      tile[(nn + 1) * 68 + k] = v.y;
      tile[(nn + 2) * 68 + k] = v.z;
      tile[(nn + 3) * 68 + k] = v.w;
    }
    __syncthreads();
#pragma unroll
    for (int it = 0; it < 2; ++it) {
      const int P = t + it * 256;
      const int r = P >> 3;  // n row 0..63
      const int p = P & 7;   // k chunk of 8
      const int n = n0 + r;
      const int i = n >> 7, j = n & 127;
      ushortx8 uq, ux;
#pragma unroll
      for (int e = 0; e < 8; ++e) {
        const int kg = kc * 64 + p * 8 + e;
        const int kk = kg & 127;
        const float coord = ((kg < 128) ? (float)(i + 1) : (float)(j + 1)) *
                            (6.283185307179586f / (128.0f + 1e-6f));
        const float inv = exp2f(-13.287712379549449f * (float)(kk >> 1) * (1.0f / 64.0f));
        const float arg = coord * inv;
        const float pe = (kk & 1) ? __cosf(arg) : __sinf(arg);
        const float xv = tile[r * 68 + p * 8 + e];
        ux[e] = f2bf(xv);
        uq[e] = f2bf(xv + pe);
      }
      const int sw = (p ^ (r & 7)) * 8;  // XOR-swizzled 16B sub-chunk
      *(ushortx8*)(qb + (size_t)n * 256 + kc * 64 + sw) = uq;
      *(ushortx8*)(xtb + (size_t)n * 256 + kc * 64 + sw) = ux;
    }
  }
}

// ---------------------------------------------------------------------------
// Per block: (4 x 128-n tiles, hv, z). Wave w owns head hv*4+w.
// k-chunks of qkT/xT staged in LDS via global_load_lds, shared by all waves;
// B-frags (Wk/Wv) prefetched to regs under the staging drain. Per-head LN
// in-wave, K^T/V^T LDS relayout, S-MFMA accumulated across n-tiles, then one
// atomicAdd per thread block.
#define LDC 72
#define NT 4
__global__ __launch_bounds__(256, 2) void kv_scores(
    const ushort* __restrict__ qkT, const ushort* __restrict__ xT,
    const ushort* __restrict__ Wkbf, const ushort* __restrict__ Wvbf,
    const float* __restrict__ bk, const float* __restrict__ bv,
    const float* __restrict__ gK, const float* __restrict__ bKp,
    const float* __restrict__ gV, const float* __restrict__ bVp,
    float* __restrict__ scores) {
  __shared__ ushort SQ[128 * 64];   // staged qkT k-chunk (swizzled)
  __shared__ ushort SX[128 * 64];   // staged xT k-chunk (swizzled)
  __shared__ ushort KT[128 * LDC];
  __shared__ ushort VT[128 * LDC];
  const int t = (int)threadIdx.x, lane = t & 63, w = t >> 6;
  const int l15 = lane & 15, l4 = lane >> 4;
  const int hv = (int)blockIdx.y, z = (int)blockIdx.z;
  const ushort* qb = qkT + (size_t)z * 16384 * 256;
  const ushort* xb = xT + (size_t)z * 16384 * 256;
  const int ocb = hv * 128 + w * 32;
  const int h = hv * 4 + w;
  // biases + LN params (per-head, loop-invariant)
  const float bkv[2] = {bk[ocb + l15], bk[ocb + 16 + l15]};
  const float bvv[2] = {bv[ocb + l15], bv[ocb + 16 + l15]};
  const float gk0 = gK[h * 32 + l15], gk1 = gK[h * 32 + 16 + l15];
  const float ok0 = bKp[h * 32 + l15], ok1 = bKp[h * 32 + 16 + l15];
  const float gv0 = gV[h * 32 + l15], gv1 = gV[h * 32 + 16 + l15];
  const float ov0 = bVp[h * 32 + l15], ov1 = bVp[h * 32 + 16 + l15];
  // staging geometry: wave w copies rows [w*32, w*32+32), 8 rows per issue
  const int srow = w * 32 + (lane >> 3);
  const int scol = (lane & 7) * 8;          // ushort offset of 16B sub-chunk
  const int rsw = l15 & 7;                  // read-side swizzle key
  floatx4 sacc[2][2] = {};
  for (int nt = 0; nt < NT; ++nt) {
    const int n0 = ((int)blockIdx.x * NT + nt) * 128;
    floatx4 acck[2][8] = {};
    floatx4 accv[2][8] = {};
    for (int kc = 0; kc < 4; ++kc) {
      __syncthreads();  // prior LDS consumers done
#pragma unroll
      for (int j = 0; j < 4; ++j) {
        const int r = srow + j * 8;
        const size_t go = (size_t)(n0 + r) * 256 + kc * 64 + scol;
        gl_lds16(qb + go, SQ + w * 2048 + j * 512);
        gl_lds16(xb + go, SX + w * 2048 + j * 512);
      }
      // prefetch B-frags for both half-steps under the staging drain
      bf16x8 Bk[2][2], Bv[2][2];
#pragma unroll
      for (int ci = 0; ci < 2; ++ci) {
        const int kb = (kc * 2 + ci) * 32 + l4 * 8;
        Bk[ci][0] = frag(Wkbf + (ocb + l15) * 256 + kb);
        Bk[ci][1] = frag(Wkbf + (ocb + 16 + l15) * 256 + kb);
        Bv[ci][0] = frag(Wvbf + (ocb + l15) * 256 + kb);
        Bv[ci][1] = frag(Wvbf + (ocb + 16 + l15) * 256 + kb);
      }
      __syncthreads();  // staging complete (vmcnt drain)
#pragma unroll
      for (int ci = 0; ci < 2; ++ci) {
#pragma unroll
        for (int m = 0; m < 8; ++m) {
          const int row = m * 16 + l15;
          const int off = row * 64 + ((ci * 4 + l4) ^ rsw) * 8;
          const bf16x8 aq = *(const bf16x8*)(SQ + off);
          const bf16x8 ax = *(const bf16x8*)(SX + off);
          acck[0][m] = mfma16(aq, Bk[ci][0], acck[0][m]);
          acck[1][m] = mfma16(aq, Bk[ci][1], acck[1][m]);
          accv[0][m] = mfma16(ax, Bv[ci][0], accv[0][m]);
          accv[1][m] = mfma16(ax, Bv[ci][1], accv[1][m]);
        }
      }
    }
    // bias
#pragma unroll
    for (int tt = 0; tt < 2; ++tt)
#pragma unroll
      for (int m = 0; m < 8; ++m)
#pragma unroll
        for (int r = 0; r < 4; ++r) {
          acck[tt][m][r] += bkv[tt];
          accv[tt][m][r] += bvv[tt];
        }
    // per-head LN over 32 channels (tt pair x 16 l15 lanes) per (m,r) row
#pragma unroll
    for (int m = 0; m < 8; ++m) {
#pragma unroll
      for (int r = 0; r < 4; ++r) {
        {
          const float a0 = acck[0][m][r], a1 = acck[1][m][r];
          float s = a0 + a1, q = a0 * a0 + a1 * a1;
#pragma unroll
          for (int msk = 1; msk < 16; msk <<= 1) {
            s += __shfl_xor(s, msk);
            q += __shfl_xor(q, msk);
          }
          const float mu = s * (1.0f / 32.0f);
          const float rstd = rsqrtf(q * (1.0f / 32.0f) - mu * mu + 1e-5f);
          acck[0][m][r] = (a0 - mu) * rstd * gk0 + ok0;
          acck[1][m][r] = (a1 - mu) * rstd * gk1 + ok1;
        }
        {
          const float a0 = accv[0][m][r], a1 = accv[1][m][r];
          float s = a0 + a1, q = a0 * a0 + a1 * a1;
#pragma unroll
          for (int msk = 1; msk < 16; msk <<= 1) {
            s += __shfl_xor(s, msk);
            q += __shfl_xor(q, msk);
          }
          const float mu = s * (1.0f / 32.0f);
          const float rstd = rsqrtf(q * (1.0f / 32.0f) - mu * mu + 1e-5f);
          accv[0][m][r] = (a0 - mu) * rstd * gv0 + ov0;
          accv[1][m][r] = (a1 - mu) * rstd * gv1 + ov1;
        }
      }
    }
    // K^T/V^T relayout + S-MFMA (accumulates across n-tiles).
#pragma unroll
    for (int half = 0; half < 2; ++half) {
      __syncthreads();
#pragma unroll
      for (int tt = 0; tt < 2; ++tt) {
        const int ch = w * 32 + tt * 16 + l15;
#pragma unroll
        for (int mm = 0; mm < 4; ++mm) {
          const int m = half * 4 + mm;
          const int col = mm * 16 + l4 * 4;
          ushort4 uk = {f2bf(acck[tt][m][0]), f2bf(acck[tt][m][1]),
                        f2bf(acck[tt][m][2]), f2bf(acck[tt][m][3])};
          ushort4 uv = {f2bf(accv[tt][m][0]), f2bf(accv[tt][m][1]),
                        f2bf(accv[tt][m][2]), f2bf(accv[tt][m][3])};
          *(ushort4*)(KT + ch * LDC + col) = uk;
          *(ushort4*)(VT + ch * LDC + col) = uv;
        }
      }
      __syncthreads();
#pragma unroll
      for (int nk = 0; nk < 2; ++nk) {
        const int ko = nk * 32 + l4 * 8;
        const bf16x8 ka0 = *(const bf16x8*)(KT + (w * 32 + l15) * LDC + ko);
        const bf16x8 ka1 = *(const bf16x8*)(KT + (w * 32 + 16 + l15) * LDC + ko);
        const bf16x8 vb0 = *(const bf16x8*)(VT + (w * 32 + l15) * LDC + ko);
        const bf16x8 vb1 = *(const bf16x8*)(VT + (w * 32 + 16 + l15) * LDC + ko);
        sacc[0][0] = mfma16(ka0, vb0, sacc[0][0]);
        sacc[0][1] = mfma16(ka0, vb1, sacc[0][1]);
        sacc[1][0] = mfma16(ka1, vb0, sacc[1][0]);
        sacc[1][1] = mfma16(ka1, vb1, sacc[1][1]);
      }
    }
  }
#pragma unroll
  for (int di = 0; di < 2; ++di)
#pragma unroll
    for (int ej = 0; ej < 2; ++ej)
#pragma unroll
      for (int r = 0; r < 4; ++r) {
        const int d = di * 16 + l4 * 4 + r;
        const int e = ej * 16 + l15;
        atomicAdd(scores + ((size_t)(z * 8 + h) * 32 + d) * 32 + e, sacc[di][ej][r]);
      }
}

// ---------------------------------------------------------------------------
// W2bf[z][he][r] = sum_d Wq[hd][r] S'[d][e] / n ; b2 = bq-fold / n.
__global__ __launch_bounds__(256) void w2_kernel(
    const float* __restrict__ Wq, const float* __restrict__ bq,
    const float* __restrict__ scores, ushort* __restrict__ W2bf,
    float* __restrict__ b2) {
  const int z = (int)blockIdx.y;
  const int row = (int)blockIdx.x;
  const int t = (int)threadIdx.x;
  const float inv_n = 1.0f / 16384.0f;
  const float* sc = scores + (size_t)z * 8192;
  if (row < 256) {
    const int h = row >> 5, e = row & 31;
    float s = 0.0f;
#pragma unroll
    for (int d = 0; d < 32; ++d)
      s += Wq[(h * 32 + d) * 256 + t] * sc[(h * 32 + d) * 32 + e];
    W2bf[(size_t)z * 65536 + row * 256 + t] = f2bf(s * inv_n);
  } else {
    const int h = t >> 5, e = t & 31;
    float s = 0.0f;
#pragma unroll
    for (int d = 0; d < 32; ++d)
      s += bq[h * 32 + d] * sc[(h * 32 + d) * 32 + e];
    b2[z * 256 + t] = s * inv_n;
  }
}

// ---------------------------------------------------------------------------
// out = LN(2*(qk_in W2^T + b2)) stored NCHW. 64-n tile, wave w owns m-tile w.
// qkT is XOR-swizzled: sub-chunk lc read at lc ^ (row&7).
__global__ __launch_bounds__(256, 2) void out_kernel(
    const ushort* __restrict__ qkT, const ushort* __restrict__ W2bf,
    const float* __restrict__ b2, const float* __restrict__ g_ln,
    const float* __restrict__ b_ln, float* __restrict__ out, int b0) {
  const int t = (int)threadIdx.x, lane = t & 63, w = t >> 6;
  const int l15 = lane & 15, l4 = lane >> 4;
  const int z = (int)blockIdx.y, b = b0 + z;
  const int n0 = (int)blockIdx.x * 64;
  const ushort* qb = qkT + (size_t)z * 16384 * 256;
  const ushort* W2b = W2bf + (size_t)z * 65536;
  const int row = n0 + w * 16 + l15;
  const int rsw = l15 & 7;
  floatx4 acc[16] = {};
#pragma unroll
  for (int c = 0; c < 8; ++c) {
    const int kb = c * 32 + l4 * 8;
    const int off = (c >> 1) * 64 + ((((c & 1) * 4 + l4) ^ rsw)) * 8;
    const bf16x8 a = frag(qb + (size_t)row * 256 + off);
#pragma unroll
    for (int tt = 0; tt < 16; ++tt) {
      const bf16x8 bb = frag(W2b + (tt * 16 + l15) * 256 + kb);
      acc[tt] = mfma16(a, bb, acc[tt]);
    }
  }
  // +b2, double, LN over 256 channels, NCHW store
#pragma unroll
  for (int tt = 0; tt < 16; ++tt) {
    const float b2v = b2[z * 256 + tt * 16 + l15];
#pragma unroll
    for (int r = 0; r < 4; ++r) acc[tt][r] = 2.0f * (acc[tt][r] + b2v);
  }
  float mean[4], rstd[4];
#pragma unroll
  for (int r = 0; r < 4; ++r) {
    float s = 0.0f, q = 0.0f;
#pragma unroll
    for (int tt = 0; tt < 16; ++tt) {
      const float v = acc[tt][r];
      s += v;
      q += v * v;
    }
#pragma unroll
    for (int msk = 1; msk < 16; msk <<= 1) {
      s += __shfl_xor(s, msk);
      q += __shfl_xor(q, msk);
    }
    const float mu = s * (1.0f / 256.0f);
    mean[r] = mu;
    rstd[r] = rsqrtf(q * (1.0f / 256.0f) - mu * mu + 1e-5f);
  }
#pragma unroll
  for (int tt = 0; tt < 16; ++tt) {
    const int c = tt * 16 + l15;
    const float g = g_ln[c], be = b_ln[c];
    float4 o;
    o.x = (acc[tt][0] - mean[0]) * rstd[0] * g + be;
    o.y = (acc[tt][1] - mean[1]) * rstd[1] * g + be;
    o.z = (acc[tt][2] - mean[2]) * rstd[2] * g + be;
    o.w = (acc[tt][3] - mean[3]) * rstd[3] * g + be;
    *(float4*)(out + (size_t)(b * 256 + c) * 16384 + n0 + w * 16 + l4 * 4) = o;
  }
}

// ---------------------------------------------------------------------------
extern "C" void kernel_launch(void* const* d_in, const int* in_sizes, int n_in,
                              void* d_out, int out_size, void* d_ws, size_t ws_size,
                              hipStream_t stream) {
  (void)in_sizes; (void)n_in; (void)out_size;
  const float* x   = (const float*)d_in[0];
  const float* Wq  = (const float*)d_in[1];
  const float* bq  = (const float*)d_in[2];
  const float* Wk  = (const float*)d_in[3];
  const float* bk  = (const float*)d_in[4];
  const float* Wv  = (const float*)d_in[5];
  const float* bv  = (const float*)d_in[6];
  const float* gK  = (const float*)d_in[7];
  const float* bK  = (const float*)d_in[8];
  const float* gV  = (const float*)d_in[9];
  const float* bV  = (const float*)d_in[10];
  const float* gln = (const float*)d_in[11];
  const float* bln = (const float*)d_in[12];
  float* out = (float*)d_out;

  // Per-batch group buffers; pick largest g in {8,4,2,1} that fits ws_size.
  const size_t PB = 16384ULL * 256 * 2;  // 8,388,608 (qkT or xT per batch)
  const size_t W2SZ = 131072, SCSZ = 32768, B2SZ = 1024, WKV = 262144;
  int g = 8;
  while (g > 1 && ws_size < (size_t)g * (2 * PB + W2SZ + SCSZ + B2SZ) + WKV) g >>= 1;
  // g=1 needs 17,204,224 B <= R1's proven-safe 18,096,128 B.

  char* p = (char*)d_ws;
  ushort* qkT   = (ushort*)p; p += (size_t)g * PB;
  ushort* xT    = (ushort*)p; p += (size_t)g * PB;
  ushort* Wkbf  = (ushort*)p; p += 131072;
  ushort* Wvbf  = (ushort*)p; p += 131072;
  ushort* W2bf  = (ushort*)p; p += (size_t)g * W2SZ;
  float*  scores = (float*)p; p += (size_t)g * SCSZ;
  float*  b2    = (float*)p;

  prep_w<<<dim3(64), 256, 0, stream>>>(Wk, Wv, Wkbf, Wvbf);
  for (int b0 = 0; b0 < 8; b0 += g) {
    hipMemsetAsync(scores, 0, (size_t)g * SCSZ, stream);
    prep_qx<<<dim3(256, g), 256, 0, stream>>>(x, qkT, xT, b0);
    kv_scores<<<dim3(128 / NT, 2, g), 256, 0, stream>>>(qkT, xT, Wkbf, Wvbf, bk, bv,
                                                        gK, bK, gV, bV, scores);
    w2_kernel<<<dim3(257, g), 256, 0, stream>>>(Wq, bq, scores, W2bf, b2);
    out_kernel<<<dim3(256, g), 256, 0, stream>>>(qkT, W2bf, b2, gln, bln, out, b0);
  }
}